// Round 1
// baseline (609.983 us; speedup 1.0000x reference)
//
#include <hip/hip_runtime.h>

#define NPTS 1000000
#define FDIM 64
#define CNUM 128
#define LROW 129               // padded leading dim: bank = (f + c) % 32, uniform for random c
#define PSTRIDE 8320           // 8192 sums + 128 counts per partial block

// ---------------- K1: partial cluster sums/counts ----------------
__global__ __launch_bounds__(256) void k1_partials(
    const float4* __restrict__ feats4, const int* __restrict__ labels,
    float* __restrict__ partials, int nblocks)
{
    __shared__ float lsum[FDIM * LROW];   // [f][c] padded
    __shared__ float lcount[CNUM];
    const int tid = threadIdx.x;
    for (int i = tid; i < FDIM * LROW; i += 256) lsum[i] = 0.f;
    if (tid < CNUM) lcount[tid] = 0.f;
    __syncthreads();

    for (int p = blockIdx.x * 256 + tid; p < NPTS; p += nblocks * 256) {
        const int c = labels[2 * p + 1];
        const float4* row = feats4 + (size_t)p * 16;
        #pragma unroll
        for (int jj = 0; jj < 16; ++jj) {
            float4 v = row[jj];
            const int f = jj * 4;
            atomicAdd(&lsum[(f + 0) * LROW + c], v.x);
            atomicAdd(&lsum[(f + 1) * LROW + c], v.y);
            atomicAdd(&lsum[(f + 2) * LROW + c], v.z);
            atomicAdd(&lsum[(f + 3) * LROW + c], v.w);
        }
        atomicAdd(&lcount[c], 1.0f);
    }
    __syncthreads();

    float* dst = partials + (size_t)blockIdx.x * PSTRIDE;
    for (int i = tid; i < PSTRIDE; i += 256) {
        float v = (i < 8192) ? lsum[(i >> 7) * LROW + (i & 127)] : lcount[i - 8192];
        dst[i] = v;
    }
}

// ---------------- K2: reduce partials -> means, counts ----------------
__global__ __launch_bounds__(256) void k2_reduce(
    const float* __restrict__ partials, int nblocks,
    float* __restrict__ means, float* __restrict__ counts)
{
    const int t = blockIdx.x * 256 + threadIdx.x;
    if (t >= PSTRIDE) return;
    float s = 0.f;
    #pragma unroll 4
    for (int b = 0; b < nblocks; ++b) s += partials[(size_t)b * PSTRIDE + t];
    if (t >= 8192) { counts[t - 8192] = s; return; }
    const int f = t >> 7, c = t & 127;
    float cnt = 0.f;
    #pragma unroll 4
    for (int b = 0; b < nblocks; ++b) cnt += partials[(size_t)b * PSTRIDE + 8192 + c];
    means[c * FDIM + f] = s / cnt;   // [c][f] layout
}

// ---------------- K3: per-point variance term ----------------
__global__ __launch_bounds__(256) void k3_var(
    const float4* __restrict__ feats4, const int* __restrict__ labels,
    const float* __restrict__ means, float* __restrict__ ppsum, int nblocks)
{
    __shared__ float lmu[FDIM * LROW];    // [f][c] padded
    __shared__ float lpp[CNUM];
    const int tid = threadIdx.x;
    for (int i = tid; i < FDIM * CNUM; i += 256) {
        const int c = i >> 6, f = i & 63;
        lmu[f * LROW + c] = means[i];
    }
    if (tid < CNUM) lpp[tid] = 0.f;
    __syncthreads();

    for (int p = blockIdx.x * 256 + tid; p < NPTS; p += nblocks * 256) {
        const int c = labels[2 * p + 1];
        const float4* row = feats4 + (size_t)p * 16;
        float a0 = 0.f, a1 = 0.f, a2 = 0.f, a3 = 0.f;
        #pragma unroll
        for (int jj = 0; jj < 16; ++jj) {
            float4 v = row[jj];
            const int f = jj * 4;
            float d0 = v.x - lmu[(f + 0) * LROW + c];
            float d1 = v.y - lmu[(f + 1) * LROW + c];
            float d2 = v.z - lmu[(f + 2) * LROW + c];
            float d3 = v.w - lmu[(f + 3) * LROW + c];
            a0 += d0 * d0; a1 += d1 * d1; a2 += d2 * d2; a3 += d3 * d3;
        }
        const float sq = (a0 + a1) + (a2 + a3);
        const float d = sqrtf(sq);
        const float t = d - 0.5f;            // DELTA_VAR
        if (t > 0.f) atomicAdd(&lpp[c], t * t);
    }
    __syncthreads();
    if (tid < CNUM) atomicAdd(&ppsum[tid], lpp[tid]);
}

// ---------------- K4: pairwise dist loss + final combine ----------------
__global__ __launch_bounds__(256) void k4_final(
    const float* __restrict__ means, const float* __restrict__ counts,
    const float* __restrict__ ppsum, float* __restrict__ out)
{
    __shared__ float lmu[CNUM * 65];      // [c][f] padded
    __shared__ float sdl, svar;
    const int tid = threadIdx.x;
    for (int i = tid; i < CNUM * FDIM; i += 256) {
        const int c = i >> 6, f = i & 63;
        lmu[c * 65 + f] = means[i];
    }
    if (tid == 0) { sdl = 0.f; svar = 0.f; }
    __syncthreads();

    const int i = tid >> 1;               // 0..127
    const int jbase = (tid & 1) * 64;
    float mi[FDIM];
    #pragma unroll
    for (int f = 0; f < FDIM; ++f) mi[f] = lmu[i * 65 + f];

    float dl = 0.f;
    for (int j = jbase; j < jbase + 64; ++j) {
        float s0 = 0.f, s1 = 0.f, s2 = 0.f, s3 = 0.f;
        #pragma unroll
        for (int f = 0; f < FDIM; f += 4) {
            float d0 = mi[f + 0] - lmu[j * 65 + f + 0];
            float d1 = mi[f + 1] - lmu[j * 65 + f + 1];
            float d2 = mi[f + 2] - lmu[j * 65 + f + 2];
            float d3 = mi[f + 3] - lmu[j * 65 + f + 3];
            s0 += d0 * d0; s1 += d1 * d1; s2 += d2 * d2; s3 += d3 * d3;
        }
        if (j != i) {
            const float sq = (s0 + s1) + (s2 + s3);
            const float pd = sqrtf(sq);
            const float r = 3.0f - pd;       // DELTA_DIST
            if (r > 0.f) dl += r * r;
        }
    }
    atomicAdd(&sdl, dl);
    if (tid < CNUM) atomicAdd(&svar, ppsum[tid] / counts[tid]);
    __syncthreads();
    if (tid == 0)
        out[0] = svar / (float)CNUM + sdl / (float)(CNUM * (CNUM - 1));
}

extern "C" void kernel_launch(void* const* d_in, const int* in_sizes, int n_in,
                              void* d_out, int out_size, void* d_ws, size_t ws_size,
                              hipStream_t stream) {
    const float4* feats4 = (const float4*)d_in[0];
    const int* labels    = (const int*)d_in[1];
    float* ws            = (float*)d_ws;
    float* out           = (float*)d_out;

    // workspace budget: partials (nb1 * PSTRIDE) + means(8192) + counts(128) + ppsum(128)
    int nb1 = 1024;
    {
        size_t avail = ws_size / sizeof(float);
        size_t fixed = 8192 + 128 + 128;
        if (avail > fixed) {
            size_t cap = (avail - fixed) / PSTRIDE;
            if ((size_t)nb1 > cap) nb1 = (int)cap;
        } else nb1 = 1;
        if (nb1 < 1) nb1 = 1;
    }
    float* partials = ws;
    float* means    = ws + (size_t)nb1 * PSTRIDE;
    float* counts   = means + 8192;
    float* ppsum    = counts + 128;

    hipMemsetAsync(ppsum, 0, CNUM * sizeof(float), stream);

    k1_partials<<<nb1, 256, 0, stream>>>(feats4, labels, partials, nb1);
    k2_reduce<<<(PSTRIDE + 255) / 256, 256, 0, stream>>>(partials, nb1, means, counts);
    k3_var<<<1024, 256, 0, stream>>>(feats4, labels, means, ppsum, 1024);
    k4_final<<<1, 256, 0, stream>>>(means, counts, ppsum, out);
}

// Round 2
// 441.529 us; speedup vs baseline: 1.3815x; 1.3815x over previous
//
#include <hip/hip_runtime.h>

#define NPTS 1000000
#define FDIM 64
#define CNUM 128
#define PSTRIDE 8320          // 8192 sums (f-major) + 128 counts
#define NB1 256               // k1 grid: 1 block/CU

// ---------------- K1: partial cluster sums/counts (wave-per-4-points) ----------------
// lane l holds features 4*(l&15)..+3 of point p0 + 4*s + (l>>4); 64-point batches.
__global__ __launch_bounds__(256) void k1_partials(
    const float4* __restrict__ feats4, const int* __restrict__ labels,
    float* __restrict__ partials, int nblocks)
{
    __shared__ float acc[FDIM * 129 + CNUM];   // sums [f*129 + c], cnt at FDIM*129
    const int tid = threadIdx.x;
    for (int i = tid; i < FDIM * 129 + CNUM; i += 256) acc[i] = 0.f;
    __syncthreads();
    float* cnt = acc + FDIM * 129;

    const int lane = tid & 63;
    const int k = lane & 15, g = lane >> 4;
    const int nwaves = nblocks * 4;
    const int wid = ((blockIdx.x << 8) + tid) >> 6;

    for (int b = wid; b < NPTS / 64; b += nwaves) {
        const int p0 = b * 64;
        float4 v[16];
        int c[16];
        #pragma unroll
        for (int s = 0; s < 16; ++s)
            v[s] = feats4[(size_t)(p0 + 4 * s) * 16 + lane];   // 1KB coalesced each
        #pragma unroll
        for (int s = 0; s < 16; ++s)
            c[s] = labels[2 * (p0 + 4 * s + g) + 1];           // 4-addr broadcast
        const int cc = labels[2 * (p0 + lane) + 1];            // per-lane point label

        #pragma unroll
        for (int s = 0; s < 16; ++s) {
            float* a0 = acc + c[s];
            atomicAdd(a0 + (4 * k + 0) * 129, v[s].x);         // bank (f+c)%32
            atomicAdd(a0 + (4 * k + 1) * 129, v[s].y);
            atomicAdd(a0 + (4 * k + 2) * 129, v[s].z);
            atomicAdd(a0 + (4 * k + 3) * 129, v[s].w);
        }
        atomicAdd(&cnt[cc], 1.0f);
    }
    __syncthreads();

    float* dst = partials + (size_t)blockIdx.x * PSTRIDE;
    for (int i = tid; i < 8192; i += 256)
        dst[i] = acc[(i >> 7) * 129 + (i & 127)];              // i = f*128 + c
    if (tid < CNUM) dst[8192 + tid] = cnt[tid];
}

// ---------------- K2a: counts ----------------
__global__ __launch_bounds__(64) void k2_counts(
    const float* __restrict__ partials, int nblocks, float* __restrict__ counts)
{
    const int c = blockIdx.x;
    const int lane = threadIdx.x;
    float s = 0.f;
    for (int b = lane; b < nblocks; b += 64)
        s += partials[(size_t)b * PSTRIDE + 8192 + c];
    #pragma unroll
    for (int m = 1; m < 64; m <<= 1) s += __shfl_xor(s, m);
    if (lane == 0) counts[c] = s;
}

// ---------------- K2b: means [c][f] ----------------
__global__ __launch_bounds__(256) void k2_means(
    const float* __restrict__ partials, int nblocks,
    const float* __restrict__ counts, float* __restrict__ means)
{
    const int t = blockIdx.x * 256 + threadIdx.x;   // 0..8191, f-major
    float s = 0.f;
    #pragma unroll 16
    for (int b = 0; b < nblocks; ++b)
        s += partials[(size_t)b * PSTRIDE + t];     // coalesced per instr
    const int f = t >> 7, c = t & 127;
    means[c * FDIM + f] = s / counts[c];
}

// ---------------- K3: variance term (wave-per-4-points, 8 pts/iter) ----------------
__global__ __launch_bounds__(256) void k3_var(
    const float4* __restrict__ feats4, const int* __restrict__ labels,
    const float* __restrict__ means, float* __restrict__ ppsum, int nblocks)
{
    __shared__ float4 mu4[CNUM * 17];   // [c][17] float4 (68-float padded rows)
    __shared__ float lpp[CNUM];
    const int tid = threadIdx.x;
    for (int i = tid; i < 2048; i += 256)
        mu4[(i >> 4) * 17 + (i & 15)] = ((const float4*)means)[i];
    if (tid < CNUM) lpp[tid] = 0.f;
    __syncthreads();

    const int lane = tid & 63;
    const int k = lane & 15, g = lane >> 4;
    const int nwaves = nblocks * 4;
    const int wid = ((blockIdx.x << 8) + tid) >> 6;

    for (int b = wid; b < NPTS / 8; b += nwaves) {
        const int p0 = b * 8;
        float4 v0 = feats4[(size_t)p0 * 16 + lane];        // points p0..p0+3
        float4 v1 = feats4[(size_t)p0 * 16 + 64 + lane];   // points p0+4..p0+7
        const int c0 = labels[2 * (p0 + g) + 1];
        const int c1 = labels[2 * (p0 + 4 + g) + 1];
        float4 m0 = mu4[c0 * 17 + k];
        float4 m1 = mu4[c1 * 17 + k];
        float dx, dy, dz, dw;
        dx = v0.x - m0.x; dy = v0.y - m0.y; dz = v0.z - m0.z; dw = v0.w - m0.w;
        float s0 = dx * dx + dy * dy + dz * dz + dw * dw;
        dx = v1.x - m1.x; dy = v1.y - m1.y; dz = v1.z - m1.z; dw = v1.w - m1.w;
        float s1 = dx * dx + dy * dy + dz * dz + dw * dw;
        s0 += __shfl_xor(s0, 1); s0 += __shfl_xor(s0, 2);
        s0 += __shfl_xor(s0, 4); s0 += __shfl_xor(s0, 8);
        s1 += __shfl_xor(s1, 1); s1 += __shfl_xor(s1, 2);
        s1 += __shfl_xor(s1, 4); s1 += __shfl_xor(s1, 8);
        if (k == 0) {
            const float t0 = sqrtf(s0) - 0.5f;   // DELTA_VAR
            const float t1 = sqrtf(s1) - 0.5f;
            atomicAdd(&lpp[c0], (t0 > 0.f) ? t0 * t0 : 0.f);
            atomicAdd(&lpp[c1], (t1 > 0.f) ? t1 * t1 : 0.f);
        }
    }
    __syncthreads();
    if (tid < CNUM) atomicAdd(&ppsum[tid], lpp[tid]);
}

// ---------------- K4: pairwise dist loss (one row per block) ----------------
__global__ __launch_bounds__(128) void k4_dist(
    const float* __restrict__ means, float* __restrict__ dsum)
{
    __shared__ float4 mu4[CNUM * 17];
    const int tid = threadIdx.x;
    for (int i = tid; i < 2048; i += 128)
        mu4[(i >> 4) * 17 + (i & 15)] = ((const float4*)means)[i];
    __syncthreads();
    const int i = blockIdx.x, j = tid;
    float sq = 0.f;
    #pragma unroll
    for (int q = 0; q < 16; ++q) {
        float4 a = mu4[i * 17 + q], b = mu4[j * 17 + q];
        float dx = a.x - b.x, dy = a.y - b.y, dz = a.z - b.z, dw = a.w - b.w;
        sq += dx * dx + dy * dy + dz * dz + dw * dw;
    }
    float dl = 0.f;
    if (j != i) {
        const float r = 3.0f - sqrtf(sq);   // DELTA_DIST
        if (r > 0.f) dl = r * r;
    }
    #pragma unroll
    for (int m = 1; m < 64; m <<= 1) dl += __shfl_xor(dl, m);
    if ((tid & 63) == 0) atomicAdd(dsum, dl);
}

// ---------------- K5: final combine ----------------
__global__ __launch_bounds__(128) void k5_final(
    const float* __restrict__ counts, const float* __restrict__ ppsum,
    const float* __restrict__ dsum, float* __restrict__ out)
{
    const int t = threadIdx.x;
    float v = ppsum[t] / counts[t];
    #pragma unroll
    for (int m = 1; m < 64; m <<= 1) v += __shfl_xor(v, m);
    __shared__ float sv[2];
    if ((t & 63) == 0) sv[t >> 6] = v;
    __syncthreads();
    if (t == 0)
        out[0] = (sv[0] + sv[1]) / (float)CNUM
               + dsum[0] / (float)(CNUM * (CNUM - 1));
}

extern "C" void kernel_launch(void* const* d_in, const int* in_sizes, int n_in,
                              void* d_out, int out_size, void* d_ws, size_t ws_size,
                              hipStream_t stream) {
    (void)in_sizes; (void)n_in; (void)out_size;
    const float4* feats4 = (const float4*)d_in[0];
    const int* labels    = (const int*)d_in[1];
    float* ws            = (float*)d_ws;
    float* out           = (float*)d_out;

    int nb1 = NB1;
    {
        size_t avail = ws_size / sizeof(float);
        size_t fixed = 8192 + 128 + 128 + 1;
        if (avail > fixed) {
            size_t cap = (avail - fixed) / PSTRIDE;
            if ((size_t)nb1 > cap) nb1 = (int)cap;
        } else nb1 = 1;
        if (nb1 < 1) nb1 = 1;
    }
    float* partials = ws;
    float* means    = ws + (size_t)nb1 * PSTRIDE;   // 16B-aligned (PSTRIDE*4 % 16 == 0)
    float* counts   = means + 8192;
    float* ppsum    = counts + 128;
    float* dsum     = ppsum + 128;

    hipMemsetAsync(ppsum, 0, (CNUM + 1) * sizeof(float), stream);  // ppsum + dsum

    k1_partials<<<nb1, 256, 0, stream>>>(feats4, labels, partials, nb1);
    k2_counts<<<CNUM, 64, 0, stream>>>(partials, nb1, counts);
    k2_means<<<32, 256, 0, stream>>>(partials, nb1, counts, means);
    k3_var<<<1024, 256, 0, stream>>>(feats4, labels, means, ppsum, 1024);
    k4_dist<<<CNUM, 128, 0, stream>>>(means, dsum);
    k5_final<<<1, 128, 0, stream>>>(counts, ppsum, dsum, out);
}

// Round 3
// 421.842 us; speedup vs baseline: 1.4460x; 1.0467x over previous
//
#include <hip/hip_runtime.h>

#define NPTS 1000000
#define FDIM 64
#define CNUM 128
#define PSTRIDE 8320          // 8192 sums (f-major) + 128 counts
#define NB1 1024              // k1 grid: 4 blocks/CU
#define NB3 1024              // k3 grid

// ---------------- K1: partial cluster sums/counts ----------------
// Wave-coalesced: lane l holds features 4*(l&15)..+3 of point p0+4s+(l>>4).
// 32-point batches, 8 x 1KB wave-loads kept live in registers.
__global__ __launch_bounds__(256, 4) void k1_partials(
    const float4* __restrict__ feats4, const int* __restrict__ labels,
    float* __restrict__ partials, int nblocks)
{
    __shared__ float acc[FDIM * 129 + CNUM];   // sums [f*129+c], counts at end
    const int tid = threadIdx.x;
    for (int i = tid; i < FDIM * 129 + CNUM; i += 256) acc[i] = 0.f;
    __syncthreads();
    float* cnt = acc + FDIM * 129;

    const int lane = tid & 63;
    const int k = lane & 15, g = lane >> 4;
    const int nwaves = nblocks * 4;
    const int wid = ((blockIdx.x << 8) + tid) >> 6;

    for (int b = wid; b < NPTS / 32; b += nwaves) {
        const int p0 = b * 32;
        float4 v[8];
        #pragma unroll
        for (int s = 0; s < 8; ++s)
            v[s] = feats4[(size_t)(p0 + 4 * s) * 16 + lane];   // 1KB coalesced
        const int cc = labels[2 * (p0 + (lane & 31)) + 1];     // 32 labels, coalesced

        #pragma unroll
        for (int s = 0; s < 8; ++s) {
            const int c = __shfl(cc, 4 * s + g);
            float* a0 = acc + c;
            atomicAdd(a0 + (4 * k + 0) * 129, v[s].x);         // bank (4k+j+c)%32
            atomicAdd(a0 + (4 * k + 1) * 129, v[s].y);
            atomicAdd(a0 + (4 * k + 2) * 129, v[s].z);
            atomicAdd(a0 + (4 * k + 3) * 129, v[s].w);
        }
        if (lane < 32) atomicAdd(&cnt[cc], 1.0f);
    }
    __syncthreads();

    float* dst = partials + (size_t)blockIdx.x * PSTRIDE;
    for (int i = tid; i < 8192; i += 256)
        dst[i] = acc[(i >> 7) * 129 + (i & 127)];              // i = f*128 + c
    if (tid < CNUM) dst[8192 + tid] = cnt[tid];
}

// ---------------- K2: reduce partials -> red[8320] (undivided sums + counts) ----
// red[0..8191] = cluster sums, c-major [c][f]; red[8192..8319] = counts.
__global__ __launch_bounds__(256) void k2_reduce(
    const float* __restrict__ partials, int nblocks, float* __restrict__ red)
{
    const int tid = threadIdx.x;
    const int tsub = tid & 31, grp = tid >> 5;
    const int t0 = blockIdx.x * 32;                 // 260 blocks cover 8320
    float s = 0.f;
    #pragma unroll 8
    for (int b = grp; b < nblocks; b += 8)
        s += partials[(size_t)b * PSTRIDE + t0 + tsub];   // 128B rows, coalesced
    __shared__ float lred[8][33];
    lred[grp][tsub] = s;
    __syncthreads();
    if (tid < 32) {
        float tot = 0.f;
        #pragma unroll
        for (int q = 0; q < 8; ++q) tot += lred[q][tid];
        const int t = t0 + tid;
        if (t < 8192) red[(t & 127) * FDIM + (t >> 7)] = tot;  // f-major -> c-major
        else red[t] = tot;                                      // counts
    }
}

// ---------------- K3: variance term ----------------
__global__ __launch_bounds__(256, 4) void k3_var(
    const float4* __restrict__ feats4, const int* __restrict__ labels,
    const float* __restrict__ red, float* __restrict__ ppsum, int nblocks)
{
    __shared__ float4 mu4[CNUM * 16];   // [c][16] float4 (group-shared c: no pad needed)
    __shared__ float lpp[CNUM];
    const int tid = threadIdx.x;
    for (int i = tid; i < 2048; i += 256) {
        float4 sv = ((const float4*)red)[i];
        float ci = 1.0f / red[8192 + (i >> 4)];
        mu4[i] = make_float4(sv.x * ci, sv.y * ci, sv.z * ci, sv.w * ci);
    }
    if (tid < CNUM) lpp[tid] = 0.f;
    __syncthreads();

    const int lane = tid & 63;
    const int k = lane & 15, g = lane >> 4;
    const int nwaves = nblocks * 4;
    const int wid = ((blockIdx.x << 8) + tid) >> 6;

    for (int b = wid; b < NPTS / 16; b += nwaves) {
        const int p0 = b * 16;
        float4 v[4];
        #pragma unroll
        for (int s = 0; s < 4; ++s)
            v[s] = feats4[(size_t)(p0 + 4 * s) * 16 + lane];
        const int cc = labels[2 * (p0 + (lane & 15)) + 1];

        #pragma unroll
        for (int s = 0; s < 4; ++s) {
            const int c = __shfl(cc, 4 * s + g);
            float4 m = mu4[c * 16 + k];
            float dx = v[s].x - m.x, dy = v[s].y - m.y,
                  dz = v[s].z - m.z, dw = v[s].w - m.w;
            float sq = dx * dx + dy * dy + dz * dz + dw * dw;
            sq += __shfl_xor(sq, 1); sq += __shfl_xor(sq, 2);
            sq += __shfl_xor(sq, 4); sq += __shfl_xor(sq, 8);
            if (k == 0) {
                const float t = sqrtf(sq) - 0.5f;      // DELTA_VAR
                if (t > 0.f) atomicAdd(&lpp[c], t * t);
            }
        }
    }
    __syncthreads();
    if (tid < CNUM) atomicAdd(&ppsum[tid], lpp[tid]);
}

// ---------------- K4: pairwise dist loss ----------------
__global__ __launch_bounds__(128) void k4_dist(
    const float* __restrict__ red, float* __restrict__ dsum)
{
    __shared__ float4 mu4[CNUM * 17];   // padded: lanes read different rows here
    const int tid = threadIdx.x;
    for (int i = tid; i < 2048; i += 128) {
        float4 sv = ((const float4*)red)[i];
        float ci = 1.0f / red[8192 + (i >> 4)];
        mu4[(i >> 4) * 17 + (i & 15)] =
            make_float4(sv.x * ci, sv.y * ci, sv.z * ci, sv.w * ci);
    }
    __syncthreads();
    const int i = blockIdx.x, j = tid;
    float sq = 0.f;
    #pragma unroll
    for (int q = 0; q < 16; ++q) {
        float4 a = mu4[i * 17 + q], b = mu4[j * 17 + q];
        float dx = a.x - b.x, dy = a.y - b.y, dz = a.z - b.z, dw = a.w - b.w;
        sq += dx * dx + dy * dy + dz * dz + dw * dw;
    }
    float dl = 0.f;
    if (j != i) {
        const float r = 3.0f - sqrtf(sq);   // DELTA_DIST
        if (r > 0.f) dl = r * r;
    }
    #pragma unroll
    for (int m = 1; m < 64; m <<= 1) dl += __shfl_xor(dl, m);
    if ((tid & 63) == 0) atomicAdd(dsum, dl);
}

// ---------------- K5: final combine ----------------
__global__ __launch_bounds__(128) void k5_final(
    const float* __restrict__ red, const float* __restrict__ ppsum,
    const float* __restrict__ dsum, float* __restrict__ out)
{
    const int t = threadIdx.x;
    float v = ppsum[t] / red[8192 + t];
    #pragma unroll
    for (int m = 1; m < 64; m <<= 1) v += __shfl_xor(v, m);
    __shared__ float sv[2];
    if ((t & 63) == 0) sv[t >> 6] = v;
    __syncthreads();
    if (t == 0)
        out[0] = (sv[0] + sv[1]) / (float)CNUM
               + dsum[0] / (float)(CNUM * (CNUM - 1));
}

extern "C" void kernel_launch(void* const* d_in, const int* in_sizes, int n_in,
                              void* d_out, int out_size, void* d_ws, size_t ws_size,
                              hipStream_t stream) {
    (void)in_sizes; (void)n_in; (void)out_size;
    const float4* feats4 = (const float4*)d_in[0];
    const int* labels    = (const int*)d_in[1];
    float* ws            = (float*)d_ws;
    float* out           = (float*)d_out;

    int nb1 = NB1;
    {
        size_t avail = ws_size / sizeof(float);
        size_t fixed = PSTRIDE + 128 + 1;           // red + ppsum + dsum
        if (avail > fixed) {
            size_t cap = (avail - fixed) / PSTRIDE;
            if ((size_t)nb1 > cap) nb1 = (int)cap;
        } else nb1 = 1;
        if (nb1 < 1) nb1 = 1;
    }
    float* partials = ws;
    float* red      = ws + (size_t)nb1 * PSTRIDE;   // 16B-aligned (PSTRIDE%4==0)
    float* ppsum    = red + PSTRIDE;
    float* dsum     = ppsum + 128;

    hipMemsetAsync(ppsum, 0, (CNUM + 1) * sizeof(float), stream);

    const int nblk2 = PSTRIDE / 32;                 // 260
    k1_partials<<<nb1, 256, 0, stream>>>(feats4, labels, partials, nb1);
    k2_reduce<<<nblk2, 256, 0, stream>>>(partials, nb1, red);
    k3_var<<<NB3, 256, 0, stream>>>(feats4, labels, red, ppsum, NB3);
    k4_dist<<<CNUM, 128, 0, stream>>>(red, dsum);
    k5_final<<<1, 128, 0, stream>>>(red, ppsum, dsum, out);
}

// Round 4
// 160.559 us; speedup vs baseline: 3.7991x; 2.6273x over previous
//
#include <hip/hip_runtime.h>

#define NPTS 1000000
#define FDIM 64
#define CNUM 128
#define PSTRIDE 8320          // 8192 sums [c][f] + 128 counts
#define NB1 512               // k1 grid: 2 blocks/CU
#define NB3 1024              // k3 grid

typedef _Float16 half8 __attribute__((ext_vector_type(8)));
typedef float f32x4 __attribute__((ext_vector_type(4)));

// ---------------- K1: cluster sums via MFMA (onehot^T x X), counts via LDS atomic ----
// Tile: M=16 clusters x N=16 feats x K=32 points. 8 ct x 4 nt = full 128x64 per wave.
// A/B layout (verified 16x16x32 family): lane&15 = m (A) / n (B); k = (lane>>4)*8 + i.
// C/D: col(n)=lane&15, row(m)=(lane>>4)*4+reg.
__global__ __launch_bounds__(256, 2) void k1_partials(
    const float* __restrict__ feats, const int* __restrict__ labels,
    float* __restrict__ partials, int nblocks)
{
    __shared__ float lds[CNUM * 65];     // merge buffer [c][65] (padded)
    __shared__ float cnt[CNUM];
    const int tid = threadIdx.x;
    if (tid < CNUM) cnt[tid] = 0.f;
    __syncthreads();

    const int lane = tid & 63;
    const int n15 = lane & 15;
    const int kb = (lane >> 4) * 8;      // k-group base
    const int nwaves = nblocks * 4;
    const int wid = ((blockIdx.x << 8) + tid) >> 6;

    f32x4 acc[8][4];
    #pragma unroll
    for (int ct = 0; ct < 8; ++ct)
        #pragma unroll
        for (int nt = 0; nt < 4; ++nt)
            acc[ct][nt] = (f32x4){0.f, 0.f, 0.f, 0.f};

    const int ntiles = NPTS / 32;        // 31250
    for (int t = wid; t < ntiles; t += nwaves) {
        const int p0 = t * 32;
        // labels for my k-slots (4-address broadcast per instr, L1-hot)
        int vlab[8];
        #pragma unroll
        for (int i = 0; i < 8; ++i)
            vlab[i] = labels[2 * (p0 + kb + i) + 1];
        // counts: one lane-atomic per point (1M total, hidden under HBM)
        const int myl = labels[2 * (p0 + (lane & 31)) + 1];
        if (lane < 32) atomicAdd(&cnt[myl], 1.0f);

        // B fragments: feats[p0+kb+i][nt*16 + n15], f32 -> f16
        half8 B[4];
        #pragma unroll
        for (int nt = 0; nt < 4; ++nt) {
            #pragma unroll
            for (int i = 0; i < 8; ++i) {
                float v = feats[(size_t)(p0 + kb + i) * FDIM + nt * 16 + n15];
                B[nt][i] = (_Float16)v;
            }
        }
        // A fragments (onehot) + MFMA
        #pragma unroll
        for (int ct = 0; ct < 8; ++ct) {
            const int cmine = ct * 16 + n15;
            union { unsigned u[4]; half8 h; } ua;
            #pragma unroll
            for (int j = 0; j < 4; ++j)
                ua.u[j] = ((vlab[2 * j] == cmine) ? 0x3C00u : 0u)
                        | ((vlab[2 * j + 1] == cmine) ? 0x3C000000u : 0u);
            #pragma unroll
            for (int nt = 0; nt < 4; ++nt)
                acc[ct][nt] = __builtin_amdgcn_mfma_f32_16x16x32_f16(
                    ua.h, B[nt], acc[ct][nt], 0, 0, 0);
        }
    }
    __syncthreads();

    // merge 4 waves' accumulators through LDS (serial rounds, race-free)
    const int w = tid >> 6;
    const int rowb = (lane >> 4) * 4;
    for (int r = 0; r < 4; ++r) {
        if (w == r) {
            #pragma unroll
            for (int ct = 0; ct < 8; ++ct)
                #pragma unroll
                for (int nt = 0; nt < 4; ++nt)
                    #pragma unroll
                    for (int reg = 0; reg < 4; ++reg) {
                        const int c = ct * 16 + rowb + reg;
                        const int f = nt * 16 + n15;
                        if (r == 0) lds[c * 65 + f] = acc[ct][nt][reg];
                        else        lds[c * 65 + f] += acc[ct][nt][reg];
                    }
        }
        __syncthreads();
    }

    float* dst = partials + (size_t)blockIdx.x * PSTRIDE;
    for (int i = tid; i < 8192; i += 256)
        dst[i] = lds[(i >> 6) * 65 + (i & 63)];      // [c][f] compact
    if (tid < CNUM) dst[8192 + tid] = cnt[tid];
}

// ---------------- K2: reduce partials -> red (atomic, 4-way b-split) ----------------
__global__ __launch_bounds__(256) void k2_reduce(
    const float* __restrict__ partials, int nblocks, float* __restrict__ red)
{
    const int t = (blockIdx.x % 33) * 256 + threadIdx.x;
    const int s = blockIdx.x / 33;
    if (t >= PSTRIDE) return;
    float sum = 0.f;
    #pragma unroll 4
    for (int b = s; b < nblocks; b += 4)
        sum += partials[(size_t)b * PSTRIDE + t];
    atomicAdd(&red[t], sum);
}

// ---------------- K3: variance term ----------------
__global__ __launch_bounds__(256, 4) void k3_var(
    const float4* __restrict__ feats4, const int* __restrict__ labels,
    const float* __restrict__ red, float* __restrict__ ppsum, int nblocks)
{
    __shared__ float4 mu4[CNUM * 16];   // [c][16] float4 (quarter-wave shares c)
    __shared__ float lpp[CNUM];
    const int tid = threadIdx.x;
    for (int i = tid; i < 2048; i += 256) {
        float4 sv = ((const float4*)red)[i];
        float ci = 1.0f / red[8192 + (i >> 4)];
        mu4[i] = make_float4(sv.x * ci, sv.y * ci, sv.z * ci, sv.w * ci);
    }
    if (tid < CNUM) lpp[tid] = 0.f;
    __syncthreads();

    const int lane = tid & 63;
    const int k = lane & 15, g = lane >> 4;
    const int nwaves = nblocks * 4;
    const int wid = ((blockIdx.x << 8) + tid) >> 6;

    for (int b = wid; b < NPTS / 32; b += nwaves) {
        const int p0 = b * 32;
        float4 v[8];
        #pragma unroll
        for (int s = 0; s < 8; ++s)
            v[s] = feats4[(size_t)(p0 + 4 * s) * 16 + lane];
        const int cc = labels[2 * (p0 + (lane & 31)) + 1];

        #pragma unroll
        for (int s = 0; s < 8; ++s) {
            const int c = __shfl(cc, 4 * s + g);
            float4 m = mu4[c * 16 + k];
            float dx = v[s].x - m.x, dy = v[s].y - m.y,
                  dz = v[s].z - m.z, dw = v[s].w - m.w;
            float sq = dx * dx + dy * dy + dz * dz + dw * dw;
            sq += __shfl_xor(sq, 1); sq += __shfl_xor(sq, 2);
            sq += __shfl_xor(sq, 4); sq += __shfl_xor(sq, 8);
            if (k == 0) {
                const float t = sqrtf(sq) - 0.5f;      // DELTA_VAR
                if (t > 0.f) atomicAdd(&lpp[c], t * t);
            }
        }
    }
    __syncthreads();
    if (tid < CNUM) atomicAdd(&ppsum[tid], lpp[tid]);
}

// ---------------- K4: pairwise dist loss ----------------
__global__ __launch_bounds__(128) void k4_dist(
    const float* __restrict__ red, float* __restrict__ dsum)
{
    __shared__ float4 mu4[CNUM * 17];   // padded: lanes read different rows here
    const int tid = threadIdx.x;
    for (int i = tid; i < 2048; i += 128) {
        float4 sv = ((const float4*)red)[i];
        float ci = 1.0f / red[8192 + (i >> 4)];
        mu4[(i >> 4) * 17 + (i & 15)] =
            make_float4(sv.x * ci, sv.y * ci, sv.z * ci, sv.w * ci);
    }
    __syncthreads();
    const int i = blockIdx.x, j = tid;
    float sq = 0.f;
    #pragma unroll
    for (int q = 0; q < 16; ++q) {
        float4 a = mu4[i * 17 + q], b = mu4[j * 17 + q];
        float dx = a.x - b.x, dy = a.y - b.y, dz = a.z - b.z, dw = a.w - b.w;
        sq += dx * dx + dy * dy + dz * dz + dw * dw;
    }
    float dl = 0.f;
    if (j != i) {
        const float r = 3.0f - sqrtf(sq);   // DELTA_DIST
        if (r > 0.f) dl = r * r;
    }
    #pragma unroll
    for (int m = 1; m < 64; m <<= 1) dl += __shfl_xor(dl, m);
    if ((tid & 63) == 0) atomicAdd(dsum, dl);
}

// ---------------- K5: final combine ----------------
__global__ __launch_bounds__(128) void k5_final(
    const float* __restrict__ red, const float* __restrict__ ppsum,
    const float* __restrict__ dsum, float* __restrict__ out)
{
    const int t = threadIdx.x;
    float v = ppsum[t] / red[8192 + t];
    #pragma unroll
    for (int m = 1; m < 64; m <<= 1) v += __shfl_xor(v, m);
    __shared__ float sv[2];
    if ((t & 63) == 0) sv[t >> 6] = v;
    __syncthreads();
    if (t == 0)
        out[0] = (sv[0] + sv[1]) / (float)CNUM
               + dsum[0] / (float)(CNUM * (CNUM - 1));
}

extern "C" void kernel_launch(void* const* d_in, const int* in_sizes, int n_in,
                              void* d_out, int out_size, void* d_ws, size_t ws_size,
                              hipStream_t stream) {
    (void)in_sizes; (void)n_in; (void)out_size;
    const float* feats   = (const float*)d_in[0];
    const float4* feats4 = (const float4*)d_in[0];
    const int* labels    = (const int*)d_in[1];
    float* ws            = (float*)d_ws;
    float* out           = (float*)d_out;

    int nb1 = NB1;
    {
        size_t avail = ws_size / sizeof(float);
        size_t fixed = PSTRIDE + 128 + 1;           // red + ppsum + dsum
        if (avail > fixed) {
            size_t cap = (avail - fixed) / PSTRIDE;
            if ((size_t)nb1 > cap) nb1 = (int)cap;
        } else nb1 = 1;
        if (nb1 < 1) nb1 = 1;
    }
    float* partials = ws;
    float* red      = ws + (size_t)nb1 * PSTRIDE;   // 16B-aligned (PSTRIDE%4==0)
    float* ppsum    = red + PSTRIDE;
    float* dsum     = ppsum + 128;

    // zero red + ppsum + dsum (contiguous)
    hipMemsetAsync(red, 0, (PSTRIDE + CNUM + 1) * sizeof(float), stream);

    k1_partials<<<nb1, 256, 0, stream>>>(feats, labels, partials, nb1);
    k2_reduce<<<33 * 4, 256, 0, stream>>>(partials, nb1, red);
    k3_var<<<NB3, 256, 0, stream>>>(feats4, labels, red, ppsum, NB3);
    k4_dist<<<CNUM, 128, 0, stream>>>(red, dsum);
    k5_final<<<1, 128, 0, stream>>>(red, ppsum, dsum, out);
}